// Round 6
// baseline (182.878 us; speedup 1.0000x reference)
//
#include <hip/hip_runtime.h>

// CustomMultiheadAttention on MI355X (gfx950).
// B=4 T=1024 S=1024 H=16 D=64 E=1024. Output fp32 [B,T,E].
//
// *** MEASUREMENT ROUND: kernels byte-identical to r5 (passed, 71.2us). ***
// Launch sequence: proj, cvt, attn x4, out_proj x3 (all idempotent).
// dur_r6 - dur_r5 = 3*T_attn + 2*T_out  -> per-kernel timing decomposition
// (rocprof top-5 is clogged by ~42us harness fill dispatches; our kernels
//  are each <41us and invisible, so we burn one round to measure).
//
// Workspace (22 MB):
//   [0,8MB) qs bf16 [B*H,T,D] | [8,10) kb [H,S,D] | [10,12) vt [H,D,S]
//   [12,20) ctx bf16 [B*T,E]  | [20,22) wb [E,E]

typedef __attribute__((ext_vector_type(8))) short short8v;
typedef __attribute__((ext_vector_type(4))) short short4v;
typedef __attribute__((ext_vector_type(4))) float float4v;

#define MFMA_BF16(A, B, C) __builtin_amdgcn_mfma_f32_16x16x32_bf16(A, B, C, 0, 0, 0)

#if __has_builtin(__builtin_amdgcn_exp2f)
#define EXP2F(x) __builtin_amdgcn_exp2f(x)
#else
#define EXP2F(x) exp2f(x)
#endif

#define QSCALE 0.045084220027780106f   // log2(e)/32

__device__ __forceinline__ short f2bf(float f) {
  union { float f; unsigned u; } v; v.f = f;
  unsigned r = v.u + 0x7FFFu + ((v.u >> 16) & 1u);
  return (short)(r >> 16);
}

// ---------------------------------------------------------------------------
// Kernel 1: per-head Q/K/V projections via MFMA (unchanged; passed r1/r3/r5).
// ---------------------------------------------------------------------------
__global__ __launch_bounds__(256) void proj_qkv(
    const float* __restrict__ query, const float* __restrict__ para,
    const float* __restrict__ Wq, const float* __restrict__ bq,
    const float* __restrict__ Wk, const float* __restrict__ bk,
    const float* __restrict__ Wv, const float* __restrict__ bv,
    short* __restrict__ qs, short* __restrict__ kb, short* __restrict__ vt) {
  const int task = blockIdx.x * 4 + (threadIdx.x >> 6);
  const int lane = threadIdx.x & 63;
  const int g = lane >> 4, c = lane & 15;

  const float* W;
  const float* bias;
  const float* xrow;
  int type, h, tile, bh = 0;
  if (task < 4096) {
    type = 0; bh = task >> 6; tile = task & 63; h = bh & 15;
    xrow = query + ((bh >> 4) * 1024 + tile * 16 + c) * 1024 + h * 64;
    W = Wq; bias = bq;
  } else if (task < 5120) {
    int idx = task - 4096;
    type = 1; h = idx >> 6; tile = idx & 63;
    xrow = para + (tile * 16 + c) * 1024 + h * 64;
    W = Wk; bias = bk;
  } else {
    int idx = task - 5120;
    type = 2; h = idx >> 6; tile = idx & 63;
    xrow = para + (tile * 16 + c) * 1024 + h * 64;
    W = Wv; bias = bv;
  }

  short8v af[2];
#pragma unroll
  for (int kh = 0; kh < 2; ++kh) {
    const float* xp = xrow + kh * 32 + g * 8;
    float4v x0 = *(const float4v*)xp;
    float4v x1 = *(const float4v*)(xp + 4);
    af[kh] = (short8v){ f2bf(x0.x), f2bf(x0.y), f2bf(x0.z), f2bf(x0.w),
                        f2bf(x1.x), f2bf(x1.y), f2bf(x1.z), f2bf(x1.w) };
  }

#pragma unroll
  for (int dn = 0; dn < 4; ++dn) {
    float4v acc = (float4v){0.f, 0.f, 0.f, 0.f};
#pragma unroll
    for (int kh = 0; kh < 2; ++kh) {
      const float* wp = W + (dn * 16 + c) * 64 + kh * 32 + g * 8;
      float4v w0 = *(const float4v*)wp;
      float4v w1 = *(const float4v*)(wp + 4);
      short8v bfr = (short8v){ f2bf(w0.x), f2bf(w0.y), f2bf(w0.z), f2bf(w0.w),
                               f2bf(w1.x), f2bf(w1.y), f2bf(w1.z), f2bf(w1.w) };
      acc = MFMA_BF16(af[kh], bfr, acc);
    }
    const float bc = bias[dn * 16 + c];
    if (type == 0) {
#pragma unroll
      for (int r = 0; r < 4; ++r) {
        const int t = tile * 16 + 4 * g + r;
        qs[(bh * 1024 + t) * 64 + dn * 16 + c] = f2bf((acc[r] + bc) * QSCALE);
      }
    } else if (type == 1) {
#pragma unroll
      for (int r = 0; r < 4; ++r) {
        const int s = tile * 16 + 4 * g + r;
        kb[(h * 1024 + s) * 64 + dn * 16 + c] = f2bf(acc[r] + bc);
      }
    } else {
      short4v pk = (short4v){ f2bf(acc[0] + bc), f2bf(acc[1] + bc),
                              f2bf(acc[2] + bc), f2bf(acc[3] + bc) };
      *(short4v*)(vt + (h * 64 + dn * 16 + c) * 1024 + tile * 16 + 4 * g) = pk;
    }
  }
}

// ---------------------------------------------------------------------------
// Kernel 2: Wout fp32 -> bf16
// ---------------------------------------------------------------------------
__global__ __launch_bounds__(256) void cvt_wout(const float* __restrict__ wsrc,
                                                short* __restrict__ wdst) {
  const int i = (blockIdx.x * 256 + threadIdx.x) * 8;
  float4v x0 = *(const float4v*)(wsrc + i);
  float4v x1 = *(const float4v*)(wsrc + i + 4);
  short8v v = (short8v){ f2bf(x0.x), f2bf(x0.y), f2bf(x0.z), f2bf(x0.w),
                         f2bf(x1.x), f2bf(x1.y), f2bf(x1.z), f2bf(x1.w) };
  *(short8v*)(wdst + i) = v;
}

// ---------------------------------------------------------------------------
// Kernel 3: attention (identical to r5; passed).
// ---------------------------------------------------------------------------
__global__ __launch_bounds__(256, 4) void attn_fwd(
    const short* __restrict__ qs, const short* __restrict__ kb,
    const short* __restrict__ vt, short* __restrict__ ctx) {
  __shared__ __align__(16) short kv[2][4096];         // per buf: K 4KB | V 4KB
  __shared__ __align__(16) short plds[4][2][16][40];  // per-wave P tiles
  const int tid = threadIdx.x;
  const int w = tid >> 6;
  const int lane = tid & 63;
  const int g = lane >> 4, c = lane & 15;
  const int bh = blockIdx.x & 63;          // XCD-swizzle: bh%8 == XCD
  const int b = bh >> 4, h = bh & 15;
  const int t0 = (blockIdx.x >> 6) * 128 + w * 32;

  const int kr = tid >> 3, kq = (tid & 7) ^ (kr & 7);
  const char* ksrc = (const char*)(kb + h * 65536) + kr * 128 + kq * 16;
  const int vd = tid >> 2, vq = (tid & 3) ^ ((vd >> 1) & 3);
  const char* vsrc = (const char*)(vt + h * 65536) + vd * 2048 + vq * 16;
  char* kdst = (char*)&kv[0][0] + tid * 16;
  char* vdst = (char*)&kv[0][0] + 4096 + tid * 16;

  int koff[2][2];
#pragma unroll
  for (int sm = 0; sm < 2; ++sm)
#pragma unroll
    for (int kh = 0; kh < 2; ++kh)
      koff[sm][kh] = (sm * 16 + c) * 128 + (((kh * 4 + g) ^ (c & 7)) * 16);
  int voff[4];
#pragma unroll
  for (int nt = 0; nt < 4; ++nt)
    voff[nt] = 4096 + (nt * 16 + c) * 64 + ((g ^ ((c >> 1) & 3)) * 16);

  const short* qbase = qs + (bh * 1024 + t0) * 64;
  short8v qf[2][2];
#pragma unroll
  for (int tn = 0; tn < 2; ++tn)
#pragma unroll
    for (int kh = 0; kh < 2; ++kh)
      qf[tn][kh] = *(const short8v*)(qbase + (tn * 16 + c) * 64 + kh * 32 + g * 8);

  float4v cacc[2][4];
#pragma unroll
  for (int tn = 0; tn < 2; ++tn)
#pragma unroll
    for (int nt = 0; nt < 4; ++nt)
      cacc[tn][nt] = (float4v){0.f, 0.f, 0.f, 0.f};
  float4v dacc[2];
  dacc[0] = (float4v){0.f, 0.f, 0.f, 0.f};
  dacc[1] = (float4v){0.f, 0.f, 0.f, 0.f};
  const short obf = (short)0x3F80;   // bf16 1.0
  const short8v ones = (short8v){obf, obf, obf, obf, obf, obf, obf, obf};

  short8v sk = *(const short8v*)ksrc;
  short8v sv = *(const short8v*)vsrc;
  *(short8v*)kdst = sk;
  *(short8v*)vdst = sv;

  const char* kv0 = (const char*)&kv[0][0];
  for (int i = 0; i < 32; ++i) {
    __syncthreads();
    if (i < 31) {
      sk = *(const short8v*)(ksrc + (i + 1) * 4096);
      sv = *(const short8v*)(vsrc + (i + 1) * 64);
    }

    const char* kvb = kv0 + (i & 1) * 8192;
    short8v kf[2][2];
#pragma unroll
    for (int sm = 0; sm < 2; ++sm)
#pragma unroll
      for (int kh = 0; kh < 2; ++kh)
        kf[sm][kh] = *(const short8v*)(kvb + koff[sm][kh]);
    short8v vf[4];
#pragma unroll
    for (int nt = 0; nt < 4; ++nt)
      vf[nt] = *(const short8v*)(kvb + voff[nt]);

#pragma unroll
    for (int sm = 0; sm < 2; ++sm)
#pragma unroll
      for (int tn = 0; tn < 2; ++tn) {
        float4v z = (float4v){0.f, 0.f, 0.f, 0.f};
        z = MFMA_BF16(kf[sm][0], qf[tn][0], z);
        z = MFMA_BF16(kf[sm][1], qf[tn][1], z);
        const float p0 = EXP2F(z[0]);
        const float p1 = EXP2F(z[1]);
        const float p2 = EXP2F(z[2]);
        const float p3 = EXP2F(z[3]);
        short4v pk = (short4v){ f2bf(p0), f2bf(p1), f2bf(p2), f2bf(p3) };
        *(short4v*)&plds[w][tn][c][sm * 16 + 4 * g] = pk;
      }

    asm volatile("" ::: "memory");

    short8v pa[2];
#pragma unroll
    for (int tn = 0; tn < 2; ++tn)
      pa[tn] = *(const short8v*)&plds[w][tn][c][g * 8];

#pragma unroll
    for (int tn = 0; tn < 2; ++tn) {
#pragma unroll
      for (int nt = 0; nt < 4; ++nt)
        cacc[tn][nt] = MFMA_BF16(pa[tn], vf[nt], cacc[tn][nt]);
      dacc[tn] = MFMA_BF16(pa[tn], ones, dacc[tn]);
    }

    asm volatile("" ::: "memory");

    if (i < 31) {
      *(short8v*)(kdst + ((i + 1) & 1) * 8192) = sk;
      *(short8v*)(vdst + ((i + 1) & 1) * 8192) = sv;
    }
  }

  const int orow0 = b * 1024 + t0;
#pragma unroll
  for (int tn = 0; tn < 2; ++tn) {
    float inv[4];
#pragma unroll
    for (int r = 0; r < 4; ++r) inv[r] = 1.0f / dacc[tn][r];
#pragma unroll
    for (int nt = 0; nt < 4; ++nt)
#pragma unroll
      for (int r = 0; r < 4; ++r) {
        const int row = orow0 + tn * 16 + 4 * g + r;
        ctx[row * 1024 + h * 64 + nt * 16 + c] = f2bf(cacc[tn][nt][r] * inv[r]);
      }
  }
}

// ---------------------------------------------------------------------------
// Kernel 4: out = ctx(bf16) @ Wout^T + bout (identical to r3/r5; passed).
// ---------------------------------------------------------------------------
__global__ __launch_bounds__(512, 4) void out_proj(
    const short* __restrict__ ctx, const short* __restrict__ wb,
    const float* __restrict__ bout, float* __restrict__ out) {
  __shared__ __align__(16) short ab[2][6144];   // per buf: A 8KB | B 4KB
  const int w = threadIdx.x >> 6;
  const int lane = threadIdx.x & 63;
  const int g = lane >> 4, c = lane & 15;
  const int mblk = (blockIdx.x & 31) * 128;
  const int n0 = (blockIdx.x >> 5) * 64;

  const int srow = w * 16 + (lane >> 2);              // 0..127
  const int sq = (lane & 3) ^ ((lane >> 3) & 3);
  const char* asrc = (const char*)ctx + (mblk + srow) * 2048 + sq * 16;
  char* adst = (char*)&ab[0][0] + w * 1024 + lane * 16;
  const char* bsrc = (const char*)wb + (n0 + srow) * 2048 + sq * 16;  // w<4 only
  char* bdst = (char*)&ab[0][0] + 8192 + w * 1024 + lane * 16;

  const int sw = (g ^ ((c >> 1) & 3)) * 16;
  const int aoff = (w * 16 + c) * 64 + sw;
  int boff[4];
#pragma unroll
  for (int nt = 0; nt < 4; ++nt)
    boff[nt] = 8192 + (nt * 16 + c) * 64 + sw;

  float4v acc[4];
#pragma unroll
  for (int nt = 0; nt < 4; ++nt) acc[nt] = (float4v){0.f, 0.f, 0.f, 0.f};

  short8v sa = *(const short8v*)asrc;
  short8v sb = (short8v){0, 0, 0, 0, 0, 0, 0, 0};
  if (w < 4) sb = *(const short8v*)bsrc;
  *(short8v*)adst = sa;
  if (w < 4) *(short8v*)bdst = sb;

  const char* ab0 = (const char*)&ab[0][0];
  for (int i = 0; i < 32; ++i) {
    __syncthreads();
    if (i < 31) {
      sa = *(const short8v*)(asrc + (i + 1) * 64);
      if (w < 4) sb = *(const short8v*)(bsrc + (i + 1) * 64);
    }
    const char* abb = ab0 + (i & 1) * 12288;
    short8v a = *(const short8v*)(abb + aoff);
    short8v bb[4];
#pragma unroll
    for (int nt = 0; nt < 4; ++nt)
      bb[nt] = *(const short8v*)(abb + boff[nt]);
#pragma unroll
    for (int nt = 0; nt < 4; ++nt)
      acc[nt] = MFMA_BF16(a, bb[nt], acc[nt]);
    if (i < 31) {
      *(short8v*)(adst + ((i + 1) & 1) * 12288) = sa;
      if (w < 4) *(short8v*)(bdst + ((i + 1) & 1) * 12288) = sb;
    }
  }

  float bs[4];
#pragma unroll
  for (int nt = 0; nt < 4; ++nt) bs[nt] = bout[n0 + nt * 16 + c];

  const int m0 = mblk + w * 16;
#pragma unroll
  for (int nt = 0; nt < 4; ++nt)
#pragma unroll
    for (int r = 0; r < 4; ++r)
      out[(m0 + 4 * g + r) * 1024 + n0 + nt * 16 + c] = acc[nt][r] + bs[nt];
}

// ---------------------------------------------------------------------------
// MEASUREMENT LAUNCH: attn x4, out_proj x3 (idempotent; output identical).
// dur - 71.2us = 3*T_attn + 2*T_out.
// ---------------------------------------------------------------------------
extern "C" void kernel_launch(void* const* d_in, const int* in_sizes, int n_in,
                              void* d_out, int out_size, void* d_ws, size_t ws_size,
                              hipStream_t stream) {
  const float* query = (const float*)d_in[0];
  const float* para  = (const float*)d_in[1];
  const float* Wq = (const float*)d_in[2];
  const float* bq = (const float*)d_in[3];
  const float* Wk = (const float*)d_in[4];
  const float* bk = (const float*)d_in[5];
  const float* Wv = (const float*)d_in[6];
  const float* bv = (const float*)d_in[7];
  const float* Wout = (const float*)d_in[8];
  const float* bout = (const float*)d_in[9];
  float* out = (float*)d_out;

  char* ws = (char*)d_ws;
  short* qs  = (short*)(ws);                      // 8 MB
  short* kb  = (short*)(ws + (8u  << 20));        // 2 MB
  short* vt  = (short*)(ws + (10u << 20));        // 2 MB
  short* ctx = (short*)(ws + (12u << 20));        // 8 MB
  short* wb  = (short*)(ws + (20u << 20));        // 2 MB

  proj_qkv<<<dim3(1536), dim3(256), 0, stream>>>(query, para, Wq, bq, Wk, bk,
                                                 Wv, bv, qs, kb, vt);
  cvt_wout<<<dim3(512), dim3(256), 0, stream>>>(Wout, wb);
  attn_fwd<<<dim3(512), dim3(256), 0, stream>>>(qs, kb, vt, ctx);
  attn_fwd<<<dim3(512), dim3(256), 0, stream>>>(qs, kb, vt, ctx);
  attn_fwd<<<dim3(512), dim3(256), 0, stream>>>(qs, kb, vt, ctx);
  attn_fwd<<<dim3(512), dim3(256), 0, stream>>>(qs, kb, vt, ctx);
  out_proj<<<dim3(512), dim3(512), 0, stream>>>(ctx, wb, bout, out);
  out_proj<<<dim3(512), dim3(512), 0, stream>>>(ctx, wb, bout, out);
  out_proj<<<dim3(512), dim3(512), 0, stream>>>(ctx, wb, bout, out);
}

// Round 7
// 83.899 us; speedup vs baseline: 2.1797x; 2.1797x over previous
//
#include <hip/hip_runtime.h>

// CustomMultiheadAttention on MI355X (gfx950).
// B=4 T=1024 S=1024 H=16 D=64 E=1024. Output fp32 [B,T,E].
//
// r7: (1) cvt_wout fused into proj_qkv as extra wave-tasks (3 kernels total);
//     (2) out_proj: A read direct from global (was a pure LDS pass-through),
//         B LDS-staged; 8 waves re-tiled 4m x 2n (32x32/wave) -> LDS traffic
//         ~45% down; (3) attn: s_setprio(1) around MFMA clusters (T5).
// attn structure otherwise identical to r5 (passed, absmax 1.95e-3).
//
// Workspace (22 MB):
//   [0,8MB) qs bf16 [B*H,T,D] | [8,10) kb [H,S,D] | [10,12) vt [H,D,S]
//   [12,20) ctx bf16 [B*T,E]  | [20,22) wb [E,E]

typedef __attribute__((ext_vector_type(8))) short short8v;
typedef __attribute__((ext_vector_type(4))) short short4v;
typedef __attribute__((ext_vector_type(4))) float float4v;

#define MFMA_BF16(A, B, C) __builtin_amdgcn_mfma_f32_16x16x32_bf16(A, B, C, 0, 0, 0)

#if __has_builtin(__builtin_amdgcn_exp2f)
#define EXP2F(x) __builtin_amdgcn_exp2f(x)
#else
#define EXP2F(x) exp2f(x)
#endif

#define QSCALE 0.045084220027780106f   // log2(e)/32

__device__ __forceinline__ short f2bf(float f) {
  union { float f; unsigned u; } v; v.f = f;
  unsigned r = v.u + 0x7FFFu + ((v.u >> 16) & 1u);
  return (short)(r >> 16);
}

// ---------------------------------------------------------------------------
// Kernel 1: per-head Q/K/V projections via MFMA  +  Wout fp32->bf16 cvt
// (tasks 6144..6655). Proj part byte-identical to r1/r3/r5 (passed).
// ---------------------------------------------------------------------------
__global__ __launch_bounds__(256) void proj_qkv(
    const float* __restrict__ query, const float* __restrict__ para,
    const float* __restrict__ Wq, const float* __restrict__ bq,
    const float* __restrict__ Wk, const float* __restrict__ bk,
    const float* __restrict__ Wv, const float* __restrict__ bv,
    const float* __restrict__ Wout,
    short* __restrict__ qs, short* __restrict__ kb, short* __restrict__ vt,
    short* __restrict__ wb) {
  const int task = blockIdx.x * 4 + (threadIdx.x >> 6);
  const int lane = threadIdx.x & 63;
  const int g = lane >> 4, c = lane & 15;

  if (task >= 6144) {   // ---- cvt Wout -> wb (512 wave-tasks, 2048 elems each)
    const int j = task - 6144;
    const float* src = Wout + j * 2048;
    short* dst = wb + j * 2048;
#pragma unroll
    for (int it = 0; it < 4; ++it) {
      const int off = it * 512 + lane * 8;
      float4v x0 = *(const float4v*)(src + off);
      float4v x1 = *(const float4v*)(src + off + 4);
      short8v v = (short8v){ f2bf(x0.x), f2bf(x0.y), f2bf(x0.z), f2bf(x0.w),
                             f2bf(x1.x), f2bf(x1.y), f2bf(x1.z), f2bf(x1.w) };
      *(short8v*)(dst + off) = v;
    }
    return;
  }

  const float* W;
  const float* bias;
  const float* xrow;
  int type, h, tile, bh = 0;
  if (task < 4096) {
    type = 0; bh = task >> 6; tile = task & 63; h = bh & 15;
    xrow = query + ((bh >> 4) * 1024 + tile * 16 + c) * 1024 + h * 64;
    W = Wq; bias = bq;
  } else if (task < 5120) {
    int idx = task - 4096;
    type = 1; h = idx >> 6; tile = idx & 63;
    xrow = para + (tile * 16 + c) * 1024 + h * 64;
    W = Wk; bias = bk;
  } else {
    int idx = task - 5120;
    type = 2; h = idx >> 6; tile = idx & 63;
    xrow = para + (tile * 16 + c) * 1024 + h * 64;
    W = Wv; bias = bv;
  }

  short8v af[2];
#pragma unroll
  for (int kh = 0; kh < 2; ++kh) {
    const float* xp = xrow + kh * 32 + g * 8;
    float4v x0 = *(const float4v*)xp;
    float4v x1 = *(const float4v*)(xp + 4);
    af[kh] = (short8v){ f2bf(x0.x), f2bf(x0.y), f2bf(x0.z), f2bf(x0.w),
                        f2bf(x1.x), f2bf(x1.y), f2bf(x1.z), f2bf(x1.w) };
  }

#pragma unroll
  for (int dn = 0; dn < 4; ++dn) {
    float4v acc = (float4v){0.f, 0.f, 0.f, 0.f};
#pragma unroll
    for (int kh = 0; kh < 2; ++kh) {
      const float* wp = W + (dn * 16 + c) * 64 + kh * 32 + g * 8;
      float4v w0 = *(const float4v*)wp;
      float4v w1 = *(const float4v*)(wp + 4);
      short8v bfr = (short8v){ f2bf(w0.x), f2bf(w0.y), f2bf(w0.z), f2bf(w0.w),
                               f2bf(w1.x), f2bf(w1.y), f2bf(w1.z), f2bf(w1.w) };
      acc = MFMA_BF16(af[kh], bfr, acc);
    }
    const float bc = bias[dn * 16 + c];
    if (type == 0) {
#pragma unroll
      for (int r = 0; r < 4; ++r) {
        const int t = tile * 16 + 4 * g + r;
        qs[(bh * 1024 + t) * 64 + dn * 16 + c] = f2bf((acc[r] + bc) * QSCALE);
      }
    } else if (type == 1) {
#pragma unroll
      for (int r = 0; r < 4; ++r) {
        const int s = tile * 16 + 4 * g + r;
        kb[(h * 1024 + s) * 64 + dn * 16 + c] = f2bf(acc[r] + bc);
      }
    } else {
      short4v pk = (short4v){ f2bf(acc[0] + bc), f2bf(acc[1] + bc),
                              f2bf(acc[2] + bc), f2bf(acc[3] + bc) };
      *(short4v*)(vt + (h * 64 + dn * 16 + c) * 1024 + tile * 16 + 4 * g) = pk;
    }
  }
}

// ---------------------------------------------------------------------------
// Kernel 2: attention (r5 structure, + s_setprio around MFMA clusters).
// ---------------------------------------------------------------------------
__global__ __launch_bounds__(256, 4) void attn_fwd(
    const short* __restrict__ qs, const short* __restrict__ kb,
    const short* __restrict__ vt, short* __restrict__ ctx) {
  __shared__ __align__(16) short kv[2][4096];         // per buf: K 4KB | V 4KB
  __shared__ __align__(16) short plds[4][2][16][40];  // per-wave P tiles
  const int tid = threadIdx.x;
  const int w = tid >> 6;
  const int lane = tid & 63;
  const int g = lane >> 4, c = lane & 15;
  const int bh = blockIdx.x & 63;          // XCD-swizzle: bh%8 == XCD
  const int b = bh >> 4, h = bh & 15;
  const int t0 = (blockIdx.x >> 6) * 128 + w * 32;

  const int kr = tid >> 3, kq = (tid & 7) ^ (kr & 7);
  const char* ksrc = (const char*)(kb + h * 65536) + kr * 128 + kq * 16;
  const int vd = tid >> 2, vq = (tid & 3) ^ ((vd >> 1) & 3);
  const char* vsrc = (const char*)(vt + h * 65536) + vd * 2048 + vq * 16;
  char* kdst = (char*)&kv[0][0] + tid * 16;
  char* vdst = (char*)&kv[0][0] + 4096 + tid * 16;

  int koff[2][2];
#pragma unroll
  for (int sm = 0; sm < 2; ++sm)
#pragma unroll
    for (int kh = 0; kh < 2; ++kh)
      koff[sm][kh] = (sm * 16 + c) * 128 + (((kh * 4 + g) ^ (c & 7)) * 16);
  int voff[4];
#pragma unroll
  for (int nt = 0; nt < 4; ++nt)
    voff[nt] = 4096 + (nt * 16 + c) * 64 + ((g ^ ((c >> 1) & 3)) * 16);

  const short* qbase = qs + (bh * 1024 + t0) * 64;
  short8v qf[2][2];
#pragma unroll
  for (int tn = 0; tn < 2; ++tn)
#pragma unroll
    for (int kh = 0; kh < 2; ++kh)
      qf[tn][kh] = *(const short8v*)(qbase + (tn * 16 + c) * 64 + kh * 32 + g * 8);

  float4v cacc[2][4];
#pragma unroll
  for (int tn = 0; tn < 2; ++tn)
#pragma unroll
    for (int nt = 0; nt < 4; ++nt)
      cacc[tn][nt] = (float4v){0.f, 0.f, 0.f, 0.f};
  float4v dacc[2];
  dacc[0] = (float4v){0.f, 0.f, 0.f, 0.f};
  dacc[1] = (float4v){0.f, 0.f, 0.f, 0.f};
  const short obf = (short)0x3F80;   // bf16 1.0
  const short8v ones = (short8v){obf, obf, obf, obf, obf, obf, obf, obf};

  short8v sk = *(const short8v*)ksrc;
  short8v sv = *(const short8v*)vsrc;
  *(short8v*)kdst = sk;
  *(short8v*)vdst = sv;

  const char* kv0 = (const char*)&kv[0][0];
  for (int i = 0; i < 32; ++i) {
    __syncthreads();
    if (i < 31) {
      sk = *(const short8v*)(ksrc + (i + 1) * 4096);
      sv = *(const short8v*)(vsrc + (i + 1) * 64);
    }

    const char* kvb = kv0 + (i & 1) * 8192;
    short8v kf[2][2];
#pragma unroll
    for (int sm = 0; sm < 2; ++sm)
#pragma unroll
      for (int kh = 0; kh < 2; ++kh)
        kf[sm][kh] = *(const short8v*)(kvb + koff[sm][kh]);
    short8v vf[4];
#pragma unroll
    for (int nt = 0; nt < 4; ++nt)
      vf[nt] = *(const short8v*)(kvb + voff[nt]);

#pragma unroll
    for (int sm = 0; sm < 2; ++sm)
#pragma unroll
      for (int tn = 0; tn < 2; ++tn) {
        float4v z = (float4v){0.f, 0.f, 0.f, 0.f};
        __builtin_amdgcn_s_setprio(1);
        z = MFMA_BF16(kf[sm][0], qf[tn][0], z);
        z = MFMA_BF16(kf[sm][1], qf[tn][1], z);
        __builtin_amdgcn_s_setprio(0);
        const float p0 = EXP2F(z[0]);
        const float p1 = EXP2F(z[1]);
        const float p2 = EXP2F(z[2]);
        const float p3 = EXP2F(z[3]);
        short4v pk = (short4v){ f2bf(p0), f2bf(p1), f2bf(p2), f2bf(p3) };
        *(short4v*)&plds[w][tn][c][sm * 16 + 4 * g] = pk;
      }

    asm volatile("" ::: "memory");

    short8v pa[2];
#pragma unroll
    for (int tn = 0; tn < 2; ++tn)
      pa[tn] = *(const short8v*)&plds[w][tn][c][g * 8];

    __builtin_amdgcn_s_setprio(1);
#pragma unroll
    for (int tn = 0; tn < 2; ++tn) {
#pragma unroll
      for (int nt = 0; nt < 4; ++nt)
        cacc[tn][nt] = MFMA_BF16(pa[tn], vf[nt], cacc[tn][nt]);
      dacc[tn] = MFMA_BF16(pa[tn], ones, dacc[tn]);
    }
    __builtin_amdgcn_s_setprio(0);

    asm volatile("" ::: "memory");

    if (i < 31) {
      *(short8v*)(kdst + ((i + 1) & 1) * 8192) = sk;
      *(short8v*)(vdst + ((i + 1) & 1) * 8192) = sv;
    }
  }

  const int orow0 = b * 1024 + t0;
#pragma unroll
  for (int tn = 0; tn < 2; ++tn) {
    float inv[4];
#pragma unroll
    for (int r = 0; r < 4; ++r) inv[r] = 1.0f / dacc[tn][r];
#pragma unroll
    for (int nt = 0; nt < 4; ++nt)
#pragma unroll
      for (int r = 0; r < 4; ++r) {
        const int row = orow0 + tn * 16 + 4 * g + r;
        ctx[row * 1024 + h * 64 + nt * 16 + c] = f2bf(cacc[tn][nt][r] * inv[r]);
      }
  }
}

// ---------------------------------------------------------------------------
// Kernel 3: out = ctx(bf16) @ Wout^T + bout. 512 blocks (32m x 16n, 128x64
// tile) x 8 waves as 4m x 2n (32x32 per wave).
// A: DIRECT global reads (ctx is L2-resident; each wave reads only its own
//    rows -- LDS staging was a pure pass-through), 1-ahead register prefetch.
// B: LDS-staged dbuf (8-way wave reuse), same verified swizzle as r3/r5:
//    LDS_B[r][ch] = wb[n0+r][ch ^ ((r>>1)&3)], 64 rows x 4 x 16B chunks.
// ---------------------------------------------------------------------------
__global__ __launch_bounds__(512, 4) void out_proj(
    const short* __restrict__ ctx, const short* __restrict__ wb,
    const float* __restrict__ bout, float* __restrict__ out) {
  __shared__ __align__(16) short bl[2][2048];   // per buf: B 4KB
  const int w = threadIdx.x >> 6;
  const int lane = threadIdx.x & 63;
  const int g = lane >> 4, c = lane & 15;
  const int wm = w >> 1, wn = w & 1;
  const int mblk = (blockIdx.x & 31) * 128;
  const int n0 = (blockIdx.x >> 5) * 64;

  // B staging (waves 0-3): rows of 64B, 4 chunks; source chunk ^= (row>>1)&3
  const int srow = w * 16 + (lane >> 2);          // 0..63 for w<4
  const int sq = (lane & 3) ^ ((lane >> 3) & 3);
  const char* bsrc = (const char*)wb + (n0 + srow) * 2048 + sq * 16;
  char* bdst = (char*)&bl[0][0] + w * 1024 + lane * 16;

  // B read offsets: row = wn*32 + nt*16 + c -> (row>>1)&3 == (c>>1)&3
  const int sw = (g ^ ((c >> 1) & 3)) * 16;
  int boff[2];
#pragma unroll
  for (int nt = 0; nt < 2; ++nt)
    boff[nt] = (wn * 32 + nt * 16 + c) * 64 + sw;

  // A direct-global row bases: m = mblk + wm*32 + mt*16 + c, k-chunk g*8
  const short* abase[2];
#pragma unroll
  for (int mt = 0; mt < 2; ++mt)
    abase[mt] = ctx + (mblk + wm * 32 + mt * 16 + c) * 1024 + g * 8;

  float4v acc[2][2];
#pragma unroll
  for (int mt = 0; mt < 2; ++mt)
#pragma unroll
    for (int nt = 0; nt < 2; ++nt)
      acc[mt][nt] = (float4v){0.f, 0.f, 0.f, 0.f};

  // prologue: B k-tile 0 -> buf 0; A k-tile 0 -> regs
  short8v sb = (short8v){0, 0, 0, 0, 0, 0, 0, 0};
  if (w < 4) { sb = *(const short8v*)bsrc; *(short8v*)bdst = sb; }
  short8v a[2];
  a[0] = *(const short8v*)abase[0];
  a[1] = *(const short8v*)abase[1];

  const char* bl0 = (const char*)&bl[0][0];
  for (int i = 0; i < 32; ++i) {
    __syncthreads();
    short8v an[2];
    if (i < 31) {
      if (w < 4) sb = *(const short8v*)(bsrc + (i + 1) * 64);
      an[0] = *(const short8v*)(abase[0] + (i + 1) * 32);
      an[1] = *(const short8v*)(abase[1] + (i + 1) * 32);
    }
    const char* bb = bl0 + (i & 1) * 4096;
    short8v bf0 = *(const short8v*)(bb + boff[0]);
    short8v bf1 = *(const short8v*)(bb + boff[1]);
    __builtin_amdgcn_s_setprio(1);
    acc[0][0] = MFMA_BF16(a[0], bf0, acc[0][0]);
    acc[0][1] = MFMA_BF16(a[0], bf1, acc[0][1]);
    acc[1][0] = MFMA_BF16(a[1], bf0, acc[1][0]);
    acc[1][1] = MFMA_BF16(a[1], bf1, acc[1][1]);
    __builtin_amdgcn_s_setprio(0);
    if (i < 31) {
      if (w < 4) *(short8v*)(bdst + ((i + 1) & 1) * 4096) = sb;
      a[0] = an[0];
      a[1] = an[1];
    }
  }

  float bs[2];
#pragma unroll
  for (int nt = 0; nt < 2; ++nt) bs[nt] = bout[n0 + wn * 32 + nt * 16 + c];

  const int m0 = mblk + wm * 32;
#pragma unroll
  for (int mt = 0; mt < 2; ++mt)
#pragma unroll
    for (int nt = 0; nt < 2; ++nt)
#pragma unroll
      for (int r = 0; r < 4; ++r)
        out[(m0 + mt * 16 + 4 * g + r) * 1024 + n0 + wn * 32 + nt * 16 + c] =
            acc[mt][nt][r] + bs[nt];
}

// ---------------------------------------------------------------------------
extern "C" void kernel_launch(void* const* d_in, const int* in_sizes, int n_in,
                              void* d_out, int out_size, void* d_ws, size_t ws_size,
                              hipStream_t stream) {
  const float* query = (const float*)d_in[0];
  const float* para  = (const float*)d_in[1];
  const float* Wq = (const float*)d_in[2];
  const float* bq = (const float*)d_in[3];
  const float* Wk = (const float*)d_in[4];
  const float* bk = (const float*)d_in[5];
  const float* Wv = (const float*)d_in[6];
  const float* bv = (const float*)d_in[7];
  const float* Wout = (const float*)d_in[8];
  const float* bout = (const float*)d_in[9];
  float* out = (float*)d_out;

  char* ws = (char*)d_ws;
  short* qs  = (short*)(ws);                      // 8 MB
  short* kb  = (short*)(ws + (8u  << 20));        // 2 MB
  short* vt  = (short*)(ws + (10u << 20));        // 2 MB
  short* ctx = (short*)(ws + (12u << 20));        // 8 MB
  short* wb  = (short*)(ws + (20u << 20));        // 2 MB

  proj_qkv<<<dim3(1664), dim3(256), 0, stream>>>(query, para, Wq, bq, Wk, bk,
                                                 Wv, bv, Wout, qs, kb, vt, wb);
  attn_fwd<<<dim3(512), dim3(256), 0, stream>>>(qs, kb, vt, ctx);
  out_proj<<<dim3(512), dim3(512), 0, stream>>>(ctx, wb, bout, out);
}

// Round 8
// 69.278 us; speedup vs baseline: 2.6398x; 1.2111x over previous
//
#include <hip/hip_runtime.h>

// CustomMultiheadAttention on MI355X (gfx950).
// B=4 T=1024 S=1024 H=16 D=64 E=1024. Output fp32 [B,T,E].
//
// r8: recombination of validated pieces only.
//   proj_qkv : r7's fused proj + Wout-cvt (passed r7).
//   attn_fwd : r5-exact (passed r5/r6; setprio removed -- m190: hurts lockstep).
//   out_proj : r5 staging/layouts (passed r3/r5/r6) + 4m x 2n wave split
//              (split validated in r7) with A LDS-staged again (r7's A-direct
//              doubled + scattered A L2 traffic -> regression).
//
// Workspace (22 MB):
//   [0,8MB) qs bf16 [B*H,T,D] | [8,10) kb [H,S,D] | [10,12) vt [H,D,S]
//   [12,20) ctx bf16 [B*T,E]  | [20,22) wb [E,E]

typedef __attribute__((ext_vector_type(8))) short short8v;
typedef __attribute__((ext_vector_type(4))) short short4v;
typedef __attribute__((ext_vector_type(4))) float float4v;

#define MFMA_BF16(A, B, C) __builtin_amdgcn_mfma_f32_16x16x32_bf16(A, B, C, 0, 0, 0)

#if __has_builtin(__builtin_amdgcn_exp2f)
#define EXP2F(x) __builtin_amdgcn_exp2f(x)
#else
#define EXP2F(x) exp2f(x)
#endif

#define QSCALE 0.045084220027780106f   // log2(e)/32

__device__ __forceinline__ short f2bf(float f) {
  union { float f; unsigned u; } v; v.f = f;
  unsigned r = v.u + 0x7FFFu + ((v.u >> 16) & 1u);
  return (short)(r >> 16);
}

// ---------------------------------------------------------------------------
// Kernel 1: per-head Q/K/V projections via MFMA + Wout fp32->bf16 cvt
// (tasks 6144..6655). Identical to r7 (passed).
// ---------------------------------------------------------------------------
__global__ __launch_bounds__(256) void proj_qkv(
    const float* __restrict__ query, const float* __restrict__ para,
    const float* __restrict__ Wq, const float* __restrict__ bq,
    const float* __restrict__ Wk, const float* __restrict__ bk,
    const float* __restrict__ Wv, const float* __restrict__ bv,
    const float* __restrict__ Wout,
    short* __restrict__ qs, short* __restrict__ kb, short* __restrict__ vt,
    short* __restrict__ wb) {
  const int task = blockIdx.x * 4 + (threadIdx.x >> 6);
  const int lane = threadIdx.x & 63;
  const int g = lane >> 4, c = lane & 15;

  if (task >= 6144) {   // ---- cvt Wout -> wb (512 wave-tasks, 2048 elems each)
    const int j = task - 6144;
    const float* src = Wout + j * 2048;
    short* dst = wb + j * 2048;
#pragma unroll
    for (int it = 0; it < 4; ++it) {
      const int off = it * 512 + lane * 8;
      float4v x0 = *(const float4v*)(src + off);
      float4v x1 = *(const float4v*)(src + off + 4);
      short8v v = (short8v){ f2bf(x0.x), f2bf(x0.y), f2bf(x0.z), f2bf(x0.w),
                             f2bf(x1.x), f2bf(x1.y), f2bf(x1.z), f2bf(x1.w) };
      *(short8v*)(dst + off) = v;
    }
    return;
  }

  const float* W;
  const float* bias;
  const float* xrow;
  int type, h, tile, bh = 0;
  if (task < 4096) {
    type = 0; bh = task >> 6; tile = task & 63; h = bh & 15;
    xrow = query + ((bh >> 4) * 1024 + tile * 16 + c) * 1024 + h * 64;
    W = Wq; bias = bq;
  } else if (task < 5120) {
    int idx = task - 4096;
    type = 1; h = idx >> 6; tile = idx & 63;
    xrow = para + (tile * 16 + c) * 1024 + h * 64;
    W = Wk; bias = bk;
  } else {
    int idx = task - 5120;
    type = 2; h = idx >> 6; tile = idx & 63;
    xrow = para + (tile * 16 + c) * 1024 + h * 64;
    W = Wv; bias = bv;
  }

  short8v af[2];
#pragma unroll
  for (int kh = 0; kh < 2; ++kh) {
    const float* xp = xrow + kh * 32 + g * 8;
    float4v x0 = *(const float4v*)xp;
    float4v x1 = *(const float4v*)(xp + 4);
    af[kh] = (short8v){ f2bf(x0.x), f2bf(x0.y), f2bf(x0.z), f2bf(x0.w),
                        f2bf(x1.x), f2bf(x1.y), f2bf(x1.z), f2bf(x1.w) };
  }

#pragma unroll
  for (int dn = 0; dn < 4; ++dn) {
    float4v acc = (float4v){0.f, 0.f, 0.f, 0.f};
#pragma unroll
    for (int kh = 0; kh < 2; ++kh) {
      const float* wp = W + (dn * 16 + c) * 64 + kh * 32 + g * 8;
      float4v w0 = *(const float4v*)wp;
      float4v w1 = *(const float4v*)(wp + 4);
      short8v bfr = (short8v){ f2bf(w0.x), f2bf(w0.y), f2bf(w0.z), f2bf(w0.w),
                               f2bf(w1.x), f2bf(w1.y), f2bf(w1.z), f2bf(w1.w) };
      acc = MFMA_BF16(af[kh], bfr, acc);
    }
    const float bc = bias[dn * 16 + c];
    if (type == 0) {
#pragma unroll
      for (int r = 0; r < 4; ++r) {
        const int t = tile * 16 + 4 * g + r;
        qs[(bh * 1024 + t) * 64 + dn * 16 + c] = f2bf((acc[r] + bc) * QSCALE);
      }
    } else if (type == 1) {
#pragma unroll
      for (int r = 0; r < 4; ++r) {
        const int s = tile * 16 + 4 * g + r;
        kb[(h * 1024 + s) * 64 + dn * 16 + c] = f2bf(acc[r] + bc);
      }
    } else {
      short4v pk = (short4v){ f2bf(acc[0] + bc), f2bf(acc[1] + bc),
                              f2bf(acc[2] + bc), f2bf(acc[3] + bc) };
      *(short4v*)(vt + (h * 64 + dn * 16 + c) * 1024 + tile * 16 + 4 * g) = pk;
    }
  }
}

// ---------------------------------------------------------------------------
// Kernel 2: attention -- r5-exact (passed r5/r6). No setprio.
// ---------------------------------------------------------------------------
__global__ __launch_bounds__(256, 4) void attn_fwd(
    const short* __restrict__ qs, const short* __restrict__ kb,
    const short* __restrict__ vt, short* __restrict__ ctx) {
  __shared__ __align__(16) short kv[2][4096];         // per buf: K 4KB | V 4KB
  __shared__ __align__(16) short plds[4][2][16][40];  // per-wave P tiles
  const int tid = threadIdx.x;
  const int w = tid >> 6;
  const int lane = tid & 63;
  const int g = lane >> 4, c = lane & 15;
  const int bh = blockIdx.x & 63;          // XCD-swizzle: bh%8 == XCD
  const int b = bh >> 4, h = bh & 15;
  const int t0 = (blockIdx.x >> 6) * 128 + w * 32;

  const int kr = tid >> 3, kq = (tid & 7) ^ (kr & 7);
  const char* ksrc = (const char*)(kb + h * 65536) + kr * 128 + kq * 16;
  const int vd = tid >> 2, vq = (tid & 3) ^ ((vd >> 1) & 3);
  const char* vsrc = (const char*)(vt + h * 65536) + vd * 2048 + vq * 16;
  char* kdst = (char*)&kv[0][0] + tid * 16;
  char* vdst = (char*)&kv[0][0] + 4096 + tid * 16;

  int koff[2][2];
#pragma unroll
  for (int sm = 0; sm < 2; ++sm)
#pragma unroll
    for (int kh = 0; kh < 2; ++kh)
      koff[sm][kh] = (sm * 16 + c) * 128 + (((kh * 4 + g) ^ (c & 7)) * 16);
  int voff[4];
#pragma unroll
  for (int nt = 0; nt < 4; ++nt)
    voff[nt] = 4096 + (nt * 16 + c) * 64 + ((g ^ ((c >> 1) & 3)) * 16);

  const short* qbase = qs + (bh * 1024 + t0) * 64;
  short8v qf[2][2];
#pragma unroll
  for (int tn = 0; tn < 2; ++tn)
#pragma unroll
    for (int kh = 0; kh < 2; ++kh)
      qf[tn][kh] = *(const short8v*)(qbase + (tn * 16 + c) * 64 + kh * 32 + g * 8);

  float4v cacc[2][4];
#pragma unroll
  for (int tn = 0; tn < 2; ++tn)
#pragma unroll
    for (int nt = 0; nt < 4; ++nt)
      cacc[tn][nt] = (float4v){0.f, 0.f, 0.f, 0.f};
  float4v dacc[2];
  dacc[0] = (float4v){0.f, 0.f, 0.f, 0.f};
  dacc[1] = (float4v){0.f, 0.f, 0.f, 0.f};
  const short obf = (short)0x3F80;   // bf16 1.0
  const short8v ones = (short8v){obf, obf, obf, obf, obf, obf, obf, obf};

  short8v sk = *(const short8v*)ksrc;
  short8v sv = *(const short8v*)vsrc;
  *(short8v*)kdst = sk;
  *(short8v*)vdst = sv;

  const char* kv0 = (const char*)&kv[0][0];
  for (int i = 0; i < 32; ++i) {
    __syncthreads();
    if (i < 31) {
      sk = *(const short8v*)(ksrc + (i + 1) * 4096);
      sv = *(const short8v*)(vsrc + (i + 1) * 64);
    }

    const char* kvb = kv0 + (i & 1) * 8192;
    short8v kf[2][2];
#pragma unroll
    for (int sm = 0; sm < 2; ++sm)
#pragma unroll
      for (int kh = 0; kh < 2; ++kh)
        kf[sm][kh] = *(const short8v*)(kvb + koff[sm][kh]);
    short8v vf[4];
#pragma unroll
    for (int nt = 0; nt < 4; ++nt)
      vf[nt] = *(const short8v*)(kvb + voff[nt]);

#pragma unroll
    for (int sm = 0; sm < 2; ++sm)
#pragma unroll
      for (int tn = 0; tn < 2; ++tn) {
        float4v z = (float4v){0.f, 0.f, 0.f, 0.f};
        z = MFMA_BF16(kf[sm][0], qf[tn][0], z);
        z = MFMA_BF16(kf[sm][1], qf[tn][1], z);
        const float p0 = EXP2F(z[0]);
        const float p1 = EXP2F(z[1]);
        const float p2 = EXP2F(z[2]);
        const float p3 = EXP2F(z[3]);
        short4v pk = (short4v){ f2bf(p0), f2bf(p1), f2bf(p2), f2bf(p3) };
        *(short4v*)&plds[w][tn][c][sm * 16 + 4 * g] = pk;
      }

    asm volatile("" ::: "memory");

    short8v pa[2];
#pragma unroll
    for (int tn = 0; tn < 2; ++tn)
      pa[tn] = *(const short8v*)&plds[w][tn][c][g * 8];

#pragma unroll
    for (int tn = 0; tn < 2; ++tn) {
#pragma unroll
      for (int nt = 0; nt < 4; ++nt)
        cacc[tn][nt] = MFMA_BF16(pa[tn], vf[nt], cacc[tn][nt]);
      dacc[tn] = MFMA_BF16(pa[tn], ones, dacc[tn]);
    }

    asm volatile("" ::: "memory");

    if (i < 31) {
      *(short8v*)(kdst + ((i + 1) & 1) * 8192) = sk;
      *(short8v*)(vdst + ((i + 1) & 1) * 8192) = sv;
    }
  }

  const int orow0 = b * 1024 + t0;
#pragma unroll
  for (int tn = 0; tn < 2; ++tn) {
    float inv[4];
#pragma unroll
    for (int r = 0; r < 4; ++r) inv[r] = 1.0f / dacc[tn][r];
#pragma unroll
    for (int nt = 0; nt < 4; ++nt)
#pragma unroll
      for (int r = 0; r < 4; ++r) {
        const int row = orow0 + tn * 16 + 4 * g + r;
        ctx[row * 1024 + h * 64 + nt * 16 + c] = f2bf(cacc[tn][nt][r] * inv[r]);
      }
  }
}

// ---------------------------------------------------------------------------
// Kernel 3: out = ctx(bf16) @ Wout^T + bout. 512 blocks (32m x 16n, 128x64
// tile) x 8 waves as 4m x 2n (32x32 per wave). A AND B LDS-staged dbuf
// (r5's verified staging); per-wave reads: 2 A-frags + 2 B-frags per iter.
// LDS content: [r][ch] = X[r][ch ^ ((r>>1)&3)] (rows of 4 x 16B chunks).
// ---------------------------------------------------------------------------
__global__ __launch_bounds__(512, 4) void out_proj(
    const short* __restrict__ ctx, const short* __restrict__ wb,
    const float* __restrict__ bout, float* __restrict__ out) {
  __shared__ __align__(16) short ab[2][6144];   // per buf: A 8KB | B 4KB
  const int w = threadIdx.x >> 6;
  const int lane = threadIdx.x & 63;
  const int g = lane >> 4, c = lane & 15;
  const int wm = w >> 1, wn = w & 1;
  const int mblk = (blockIdx.x & 31) * 128;
  const int n0 = (blockIdx.x >> 5) * 64;

  // staging (identical to r3/r5): rows of 64B, 4 chunks; src chunk ^= (row>>1)&3
  const int srow = w * 16 + (lane >> 2);              // 0..127
  const int sq = (lane & 3) ^ ((lane >> 3) & 3);
  const char* asrc = (const char*)ctx + (mblk + srow) * 2048 + sq * 16;
  char* adst = (char*)&ab[0][0] + w * 1024 + lane * 16;
  const char* bsrc = (const char*)wb + (n0 + srow) * 2048 + sq * 16;  // w<4 only
  char* bdst = (char*)&ab[0][0] + 8192 + w * 1024 + lane * 16;

  // read offsets: row = wm*32 + mt*16 + c (A), wn*32 + nt*16 + c (B);
  // (row>>1)&3 == (c>>1)&3 since wm*32, mt*16 are multiples of 8.
  const int sw = (g ^ ((c >> 1) & 3)) * 16;
  int aoff[2], boff[2];
#pragma unroll
  for (int mt = 0; mt < 2; ++mt)
    aoff[mt] = (wm * 32 + mt * 16 + c) * 64 + sw;
#pragma unroll
  for (int nt = 0; nt < 2; ++nt)
    boff[nt] = 8192 + (wn * 32 + nt * 16 + c) * 64 + sw;

  float4v acc[2][2];
#pragma unroll
  for (int mt = 0; mt < 2; ++mt)
#pragma unroll
    for (int nt = 0; nt < 2; ++nt)
      acc[mt][nt] = (float4v){0.f, 0.f, 0.f, 0.f};

  // prologue: k-tile 0 -> buf 0
  short8v sa = *(const short8v*)asrc;
  short8v sb = (short8v){0, 0, 0, 0, 0, 0, 0, 0};
  if (w < 4) sb = *(const short8v*)bsrc;
  *(short8v*)adst = sa;
  if (w < 4) *(short8v*)bdst = sb;

  const char* ab0 = (const char*)&ab[0][0];
  for (int i = 0; i < 32; ++i) {
    __syncthreads();
    if (i < 31) {
      sa = *(const short8v*)(asrc + (i + 1) * 64);
      if (w < 4) sb = *(const short8v*)(bsrc + (i + 1) * 64);
    }
    const char* abb = ab0 + (i & 1) * 12288;
    short8v a[2], bb[2];
#pragma unroll
    for (int mt = 0; mt < 2; ++mt)
      a[mt] = *(const short8v*)(abb + aoff[mt]);
#pragma unroll
    for (int nt = 0; nt < 2; ++nt)
      bb[nt] = *(const short8v*)(abb + boff[nt]);
#pragma unroll
    for (int mt = 0; mt < 2; ++mt)
#pragma unroll
      for (int nt = 0; nt < 2; ++nt)
        acc[mt][nt] = MFMA_BF16(a[mt], bb[nt], acc[mt][nt]);
    if (i < 31) {
      *(short8v*)(adst + ((i + 1) & 1) * 12288) = sa;
      if (w < 4) *(short8v*)(bdst + ((i + 1) & 1) * 12288) = sb;
    }
  }

  float bs[2];
#pragma unroll
  for (int nt = 0; nt < 2; ++nt) bs[nt] = bout[n0 + wn * 32 + nt * 16 + c];

  const int m0 = mblk + wm * 32;
#pragma unroll
  for (int mt = 0; mt < 2; ++mt)
#pragma unroll
    for (int nt = 0; nt < 2; ++nt)
#pragma unroll
      for (int r = 0; r < 4; ++r)
        out[(m0 + mt * 16 + 4 * g + r) * 1024 + n0 + wn * 32 + nt * 16 + c] =
            acc[mt][nt][r] + bs[nt];
}

// ---------------------------------------------------------------------------
extern "C" void kernel_launch(void* const* d_in, const int* in_sizes, int n_in,
                              void* d_out, int out_size, void* d_ws, size_t ws_size,
                              hipStream_t stream) {
  const float* query = (const float*)d_in[0];
  const float* para  = (const float*)d_in[1];
  const float* Wq = (const float*)d_in[2];
  const float* bq = (const float*)d_in[3];
  const float* Wk = (const float*)d_in[4];
  const float* bk = (const float*)d_in[5];
  const float* Wv = (const float*)d_in[6];
  const float* bv = (const float*)d_in[7];
  const float* Wout = (const float*)d_in[8];
  const float* bout = (const float*)d_in[9];
  float* out = (float*)d_out;

  char* ws = (char*)d_ws;
  short* qs  = (short*)(ws);                      // 8 MB
  short* kb  = (short*)(ws + (8u  << 20));        // 2 MB
  short* vt  = (short*)(ws + (10u << 20));        // 2 MB
  short* ctx = (short*)(ws + (12u << 20));        // 8 MB
  short* wb  = (short*)(ws + (20u << 20));        // 2 MB

  proj_qkv<<<dim3(1664), dim3(256), 0, stream>>>(query, para, Wq, bq, Wk, bk,
                                                 Wv, bv, Wout, qs, kb, vt, wb);
  attn_fwd<<<dim3(512), dim3(256), 0, stream>>>(qs, kb, vt, ctx);
  out_proj<<<dim3(512), dim3(512), 0, stream>>>(ctx, wb, bout, out);
}